// Round 1
// baseline (7692.996 us; speedup 1.0000x reference)
//
#include <hip/hip_runtime.h>
#include <math.h>

#define BB 128
#define QQ 200
#define CC 92
#define NP1 201  // n+1 (1-based columns, index 0 = sentinel)

// ---------------------------------------------------------------------------
// Kernel 1: lse[b,i] = logsumexp(pred_cat[b,i,:]) over C=92 classes
// ---------------------------------------------------------------------------
__global__ void lse_kernel(const float* __restrict__ pc, float* __restrict__ lse) {
    int idx = blockIdx.x * blockDim.x + threadIdx.x;  // over B*Q
    if (idx >= BB * QQ) return;
    const float* row = pc + (size_t)idx * CC;
    float m = -INFINITY;
    for (int c = 0; c < CC; ++c) m = fmaxf(m, row[c]);
    float s = 0.f;
    for (int c = 0; c < CC; ++c) s += expf(row[c] - m);
    lse[idx] = m + logf(s);
}

// ---------------------------------------------------------------------------
// Kernel 2: cost[b,i,j] = CE + SmoothL1*mask
//   CE = lse[b,i] - pred_cat[b,i,tar_cat[b,j]]
//   SmoothL1 over 4 bbox dims, masked by tar_cat[b,j] != 0
// ---------------------------------------------------------------------------
__global__ void cost_kernel(const float* __restrict__ pc,
                            const float* __restrict__ pb,
                            const int*   __restrict__ tc,
                            const float* __restrict__ tb,
                            const float* __restrict__ lse,
                            float* __restrict__ cost) {
    long idx = blockIdx.x * (long)blockDim.x + threadIdx.x;
    if (idx >= (long)BB * QQ * QQ) return;
    int j = (int)(idx % QQ);
    int i = (int)((idx / QQ) % QQ);
    int b = (int)(idx / ((long)QQ * QQ));
    int cls = tc[b * QQ + j];
    float ce = lse[b * QQ + i] - pc[((size_t)(b * QQ + i)) * CC + cls];
    const float* pbb = pb + ((size_t)(b * QQ + i)) * 4;
    const float* tbb = tb + ((size_t)(b * QQ + j)) * 4;
    float sl1 = 0.f;
#pragma unroll
    for (int k = 0; k < 4; ++k) {
        float d = pbb[k] - tbb[k];
        float ad = fabsf(d);
        sl1 += (ad < 1.f) ? 0.5f * d * d : (ad - 0.5f);
    }
    float mask = (cls != 0) ? 1.f : 0.f;
    cost[idx] = ce + sl1 * mask;
}

// ---------------------------------------------------------------------------
// Kernel 3: Hungarian (JV augmenting path, e-maxx form) — one 64-lane wave
// per batch. Columns lane-strided (lane t owns j = t, t+64, t+128, t+192).
// State in LDS; argmin via shfl_xor butterfly with first-index tie-break
// (matches jnp.argmin). Arithmetic order replicates the JAX reference.
// ---------------------------------------------------------------------------
__global__ __launch_bounds__(64) void hungarian_kernel(const float* __restrict__ cost,
                                                       float* __restrict__ out) {
    const int b = blockIdx.x;
    const int t = threadIdx.x;
    const float* cb = cost + (size_t)b * QQ * QQ;

    __shared__ float u[NP1];
    __shared__ float v[NP1];
    __shared__ float minv[NP1];
    __shared__ int   p[NP1];
    __shared__ int   way[NP1];
    __shared__ int   used[NP1];

    const float INF = 1e9f;

    for (int j = t; j < NP1; j += 64) { u[j] = 0.f; v[j] = 0.f; p[j] = 0; }
    __syncthreads();

    for (int i = 1; i <= QQ; ++i) {
        if (t == 0) p[0] = i;
        for (int j = t; j < NP1; j += 64) { minv[j] = INF; way[j] = 0; used[j] = 0; }
        __syncthreads();

        int j0 = 0;
        while (true) {
            int i0 = p[j0];           // uniform read (same LDS address, broadcast)
            if (i0 == 0) break;       // while-loop condition: p[j0] != 0
            if (t == 0) used[j0] = 1;
            __syncthreads();

            float ui0 = u[i0];
            const float* crow = cb + (size_t)(i0 - 1) * QQ;

            // scan owned columns: update minv/way, collect local argmin candidate
            float bestv = INF;
            int   bestj = 0x7fffffff;
            for (int j = t; j <= QQ; j += 64) {
                if (j == 0) continue;
                if (!used[j]) {
                    float cur = crow[j - 1] - ui0 - v[j];   // (c - u) - v, ref order
                    if (cur < minv[j]) { minv[j] = cur; way[j] = j0; }
                    float mv = minv[j];
                    if (mv < bestv || (mv == bestv && j < bestj)) { bestv = mv; bestj = j; }
                }
            }
            // 64-lane butterfly argmin, lexicographic (value, index) min
            for (int off = 32; off > 0; off >>= 1) {
                float ov = __shfl_xor(bestv, off);
                int   oj = __shfl_xor(bestj, off);
                if (ov < bestv || (ov == bestv && oj < bestj)) { bestv = ov; bestj = oj; }
            }
            float delta = bestv;
            int   j1 = bestj;

            // potential / minv update (same ownership as scan -> no extra barrier)
            for (int j = t; j <= QQ; j += 64) {
                if (used[j]) {
                    u[p[j]] += delta;   // rows p[j] distinct for used j — no conflict
                    v[j] -= delta;
                } else {
                    minv[j] -= delta;
                }
            }
            __syncthreads();
            j0 = j1;
        }

        // augment: flip matching along alternating path (sequential, thread 0)
        if (t == 0) {
            int jj = j0;
            while (jj != 0) { int jn = way[jj]; p[jj] = p[jn]; jj = jn; }
        }
        __syncthreads();
    }

    // p[j] = row matched to column j (1-based); emit per-row matched cost
    for (int j = 1 + t; j <= QQ; j += 64) {
        int row = p[j] - 1;
        out[b * QQ + row] = cb[(size_t)row * QQ + (j - 1)];
    }
}

// ---------------------------------------------------------------------------
extern "C" void kernel_launch(void* const* d_in, const int* in_sizes, int n_in,
                              void* d_out, int out_size, void* d_ws, size_t ws_size,
                              hipStream_t stream) {
    const float* pred_cat  = (const float*)d_in[0];
    const float* pred_bbox = (const float*)d_in[1];
    const int*   tar_cat   = (const int*)d_in[2];
    const float* tar_bbox  = (const float*)d_in[3];
    float* out = (float*)d_out;

    float* cost = (float*)d_ws;                     // B*Q*Q floats = 20.48 MB
    float* lse  = cost + (size_t)BB * QQ * QQ;      // B*Q floats

    lse_kernel<<<(BB * QQ + 255) / 256, 256, 0, stream>>>(pred_cat, lse);
    cost_kernel<<<((long)BB * QQ * QQ + 255) / 256, 256, 0, stream>>>(
        pred_cat, pred_bbox, tar_cat, tar_bbox, lse, cost);
    hungarian_kernel<<<BB, 64, 0, stream>>>(cost, out);
}

// Round 2
// 2999.022 us; speedup vs baseline: 2.5652x; 2.5652x over previous
//
#include <hip/hip_runtime.h>
#include <math.h>

#define BB 128
#define QQ 200
#define CC 92
#define NP1 201  // n+1 (1-based columns, index 0 = sentinel)

// ---------------------------------------------------------------------------
// Kernel 1: lse[b,i] = logsumexp(pred_cat[b,i,:]) over C=92 classes
// ---------------------------------------------------------------------------
__global__ void lse_kernel(const float* __restrict__ pc, float* __restrict__ lse) {
    int idx = blockIdx.x * blockDim.x + threadIdx.x;  // over B*Q
    if (idx >= BB * QQ) return;
    const float* row = pc + (size_t)idx * CC;
    float m = -INFINITY;
    for (int c = 0; c < CC; ++c) m = fmaxf(m, row[c]);
    float s = 0.f;
    for (int c = 0; c < CC; ++c) s += expf(row[c] - m);
    lse[idx] = m + logf(s);
}

// ---------------------------------------------------------------------------
// Kernel 2: cost[b,i,j] = CE + SmoothL1*mask
// ---------------------------------------------------------------------------
__global__ void cost_kernel(const float* __restrict__ pc,
                            const float* __restrict__ pb,
                            const int*   __restrict__ tc,
                            const float* __restrict__ tb,
                            const float* __restrict__ lse,
                            float* __restrict__ cost) {
    long idx = blockIdx.x * (long)blockDim.x + threadIdx.x;
    if (idx >= (long)BB * QQ * QQ) return;
    int j = (int)(idx % QQ);
    int i = (int)((idx / QQ) % QQ);
    int b = (int)(idx / ((long)QQ * QQ));
    int cls = tc[b * QQ + j];
    float ce = lse[b * QQ + i] - pc[((size_t)(b * QQ + i)) * CC + cls];
    const float* pbb = pb + ((size_t)(b * QQ + i)) * 4;
    const float* tbb = tb + ((size_t)(b * QQ + j)) * 4;
    float sl1 = 0.f;
#pragma unroll
    for (int k = 0; k < 4; ++k) {
        float d = pbb[k] - tbb[k];
        float ad = fabsf(d);
        sl1 += (ad < 1.f) ? 0.5f * d * d : (ad - 0.5f);
    }
    float mask = (cls != 0) ? 1.f : 0.f;
    cost[idx] = ce + sl1 * mask;
}

// ---------------------------------------------------------------------------
// order-preserving float -> uint mapping (for exact lexicographic argmin)
// ---------------------------------------------------------------------------
__device__ __forceinline__ unsigned sortable(float f) {
    unsigned u = __float_as_uint(f);
    return u ^ ((unsigned)((int)u >> 31) | 0x80000000u);
}

// ---------------------------------------------------------------------------
// Kernel 3: Hungarian (JV augmenting path) — one 64-lane wave per batch.
// Per-lane register state: lane t owns columns j = 1+t+64k (k=0..3; k=3 only
// for t<8). minv/way/v/used live in registers; u (rows) and p/way-for-augment
// live in LDS. Single wave => LDS ops are in-order, no __syncthreads needed.
// Arithmetic replicates the JAX reference op-for-op:
//   cur   = (C[i0-1,j] - u[i0]) - v[j]        (u[i0] is phase-start value:
//            a row's u is only updated in iterations at/after its column is
//            marked used, and reads happen before that row's first update)
//   minv  = upd ? cur : minv ; then minv -= delta (unused), v -= delta (used),
//   u[p[j]] += delta (used, incl. sentinel column 0 with p[0]=i).
// ---------------------------------------------------------------------------
__global__ __launch_bounds__(64) void hungarian_kernel(const float* __restrict__ cost,
                                                       float* __restrict__ out) {
    const int b = blockIdx.x;
    const int t = threadIdx.x;
    const float* cb = cost + (size_t)b * QQ * QQ;

    __shared__ float u[NP1];
    __shared__ int   p[NP1];
    __shared__ int   wayl[NP1];

    const float INF = 1e9f;

    for (int j = t; j < NP1; j += 64) { u[j] = 0.f; p[j] = 0; }

    float v[4];      // column potentials (register, exact per-iteration updates)
    float minv[4];
    int   waysl[4];
    int   prow[4];   // cached row matched to column at its use time
    int   usedm;     // bitmask of used slots
    const int nval = (t < 8) ? 4 : 3;   // slot k valid iff 1+t+64k <= 200

    v[0] = v[1] = v[2] = v[3] = 0.f;

    for (int i = 1; i <= QQ; ++i) {
        if (t == 0) p[0] = i;   // augmentation's final step reads p[0]
        minv[0] = minv[1] = minv[2] = minv[3] = INF;
        waysl[0] = waysl[1] = waysl[2] = waysl[3] = 0;
        usedm = 0;
        int j0 = 0;
        int i0 = i;           // p[0] = i, first iteration special-cased
        for (;;) {
            // mark j0 used (owner lane); sentinel j0==0 handled by lane 0 below
            if (j0 > 0) {
                int s = (j0 - 1) >> 6;
                if (((j0 - 1) & 63) == t) { usedm |= 1 << s; prow[s] = i0; }
            }

            float u0 = u[i0];                       // LDS broadcast read
            const float* crow = cb + (size_t)(i0 - 1) * QQ;
            float c[4];
            c[0] = crow[t];
            c[1] = crow[64 + t];
            c[2] = crow[128 + t];
            c[3] = (t < 8) ? crow[192 + t] : 0.f;

            unsigned long long key = ~0ULL;
#pragma unroll
            for (int k = 0; k < 4; ++k) {
                int jc = 1 + t + 64 * k;
                bool active = (k < nval) && !(usedm & (1 << k));
                if (active) {
                    float cur = c[k] - u0 - v[k];          // ref op order
                    if (cur < minv[k]) { minv[k] = cur; waysl[k] = j0; }
                    unsigned long long kk =
                        ((unsigned long long)sortable(minv[k]) << 32) | (unsigned)jc;
                    key = (kk < key) ? kk : key;
                }
            }
            // 64-lane butterfly min on (value, j) key — exact jnp.argmin semantics
#pragma unroll
            for (int off = 32; off > 0; off >>= 1) {
                unsigned long long o =
                    (unsigned long long)__shfl_xor((long long)key, off, 64);
                key = (o < key) ? o : key;
            }
            int j1 = (int)(key & 0xffffffffu);
            unsigned hi = (unsigned)(key >> 32);
            unsigned fb = (hi & 0x80000000u) ? (hi ^ 0x80000000u) : ~hi;
            float delta = __uint_as_float(fb);

            // updates (identical single-op sequence to reference)
#pragma unroll
            for (int k = 0; k < 4; ++k) {
                if (usedm & (1 << k)) {
                    v[k] -= delta;
                    atomicAdd(&u[prow[k]], delta);   // ds_add_f32, rows distinct
                } else if (k < nval) {
                    minv[k] -= delta;
                }
            }
            if (t == 0) atomicAdd(&u[i], delta);     // sentinel column 0 (p[0]=i)

            // persist way[j1] for the augmentation walk (frozen once used)
            {
                int s = (j1 - 1) >> 6;
                if (((j1 - 1) & 63) == t) wayl[j1] = waysl[s];
            }

            int pi = p[j1];                          // LDS broadcast read
            if (pi == 0) { j0 = j1; break; }
            j0 = j1; i0 = pi;
        }
        // augment: flip matching along alternating path (lane 0, sequential)
        if (t == 0) {
            int jj = j0;
            while (jj != 0) { int jn = wayl[jj]; p[jj] = p[jn]; jj = jn; }
        }
    }

    // p[j] = row matched to column j (1-based); emit per-row matched cost
    for (int j = 1 + t; j <= QQ; j += 64) {
        int row = p[j] - 1;
        out[b * QQ + row] = cb[(size_t)row * QQ + (j - 1)];
    }
}

// ---------------------------------------------------------------------------
extern "C" void kernel_launch(void* const* d_in, const int* in_sizes, int n_in,
                              void* d_out, int out_size, void* d_ws, size_t ws_size,
                              hipStream_t stream) {
    const float* pred_cat  = (const float*)d_in[0];
    const float* pred_bbox = (const float*)d_in[1];
    const int*   tar_cat   = (const int*)d_in[2];
    const float* tar_bbox  = (const float*)d_in[3];
    float* out = (float*)d_out;

    float* cost = (float*)d_ws;                     // B*Q*Q floats = 20.48 MB
    float* lse  = cost + (size_t)BB * QQ * QQ;      // B*Q floats

    lse_kernel<<<(BB * QQ + 255) / 256, 256, 0, stream>>>(pred_cat, lse);
    cost_kernel<<<((long)BB * QQ * QQ + 255) / 256, 256, 0, stream>>>(
        pred_cat, pred_bbox, tar_cat, tar_bbox, lse, cost);
    hungarian_kernel<<<BB, 64, 0, stream>>>(cost, out);
}